// Round 4
// baseline (10409.837 us; speedup 1.0000x reference)
//
#include <hip/hip_runtime.h>

typedef __attribute__((ext_vector_type(4))) float  f32x4;
typedef __attribute__((ext_vector_type(8))) short  short8;
typedef __attribute__((ext_vector_type(4))) short  short4v;

union U8 { unsigned long long u[2]; short8 s; };

__device__ __forceinline__ float bf2f(short s){
  unsigned u = ((unsigned)(unsigned short)s) << 16;
  float f; __builtin_memcpy(&f, &u, 4); return f;
}
__device__ __forceinline__ short f2bf(float x){
  unsigned u; __builtin_memcpy(&u, &x, 4);
  u = (u + 0x7fffu + ((u >> 16) & 1u)) >> 16;
  return (short)u;
}
__device__ __forceinline__ float sigm(float x){ return 1.f / (1.f + __expf(-x)); }
__device__ __forceinline__ float ftanh(float x){ return 1.f - 2.f / (__expf(2.f * x) + 1.f); }

// ---------------------------------------------------------------------------
// Generic bf16-MFMA GEMM: C[M,N] = A[M,K] * B[K,N] + bias[N]
// ---------------------------------------------------------------------------
template<int AF32, int OF32>
__global__ __launch_bounds__(256) void gemm_bias(const void* __restrict__ Av,
                                                 const float* __restrict__ B,
                                                 const float* __restrict__ bias,
                                                 void* __restrict__ Cv,
                                                 int M, int N, int K)
{
  __shared__ __align__(16) short As[128 * 40];
  __shared__ __align__(16) short Bs[128 * 40];
  int tid  = threadIdx.x;
  int col0 = blockIdx.x * 128, row0 = blockIdx.y * 128;
  int lane = tid & 63, wave = tid >> 6;
  int wm = (wave >> 1) * 64, wn = (wave & 1) * 64;

  f32x4 acc[4][4];
  for (int mi = 0; mi < 4; mi++)
    for (int ni = 0; ni < 4; ni++)
      for (int q = 0; q < 4; q++) acc[mi][ni][q] = 0.f;

  for (int kt = 0; kt < K; kt += 32) {
    __syncthreads();
    if (AF32) {
      const float* A = (const float*)Av;
      for (int i = 0; i < 4; i++) {
        int idx = tid + i * 256;
        int r = idx >> 3, c4 = (idx & 7) << 2;
        f32x4 v = *(const f32x4*)(A + (size_t)(row0 + r) * K + kt + c4);
        short4v o;
        for (int q = 0; q < 4; q++) o[q] = f2bf(v[q]);
        *(short4v*)&As[r * 40 + c4] = o;
      }
    } else {
      const short* A = (const short*)Av;
      for (int i = 0; i < 2; i++) {
        int idx = tid + i * 256;
        int r = idx >> 2, c8 = (idx & 3) << 3;
        short8 v = *(const short8*)(A + (size_t)(row0 + r) * K + kt + c8);
        *(short8*)&As[r * 40 + c8] = v;
      }
    }
    for (int i = 0; i < 4; i++) {
      int idx = tid + i * 256;
      int kr = idx >> 5, c4 = (idx & 31) << 2;
      f32x4 v = *(const f32x4*)(B + (size_t)(kt + kr) * N + col0 + c4);
      for (int e = 0; e < 4; e++) Bs[(c4 + e) * 40 + kr] = f2bf(v[e]);
    }
    __syncthreads();

    int fr = lane & 15, fo = (lane >> 4) << 3;
    short8 af[4], bfr[4];
    for (int mi = 0; mi < 4; mi++) af[mi]  = *(short8*)&As[(wm + mi * 16 + fr) * 40 + fo];
    for (int ni = 0; ni < 4; ni++) bfr[ni] = *(short8*)&Bs[(wn + ni * 16 + fr) * 40 + fo];
    for (int mi = 0; mi < 4; mi++)
      for (int ni = 0; ni < 4; ni++)
        acc[mi][ni] = __builtin_amdgcn_mfma_f32_16x16x32_bf16(af[mi], bfr[ni], acc[mi][ni], 0, 0, 0);
  }

  int efr = lane & 15, efrow = (lane >> 4) << 2;
  for (int ni = 0; ni < 4; ni++) {
    int col = col0 + wn + ni * 16 + efr;
    float bv = bias[col];
    for (int mi = 0; mi < 4; mi++) {
      for (int q = 0; q < 4; q++) {
        int row = row0 + wm + mi * 16 + efrow + q;
        float v = acc[mi][ni][q] + bv;
        if (OF32) ((float*)Cv)[(size_t)row * N + col] = v;
        else      ((short*)Cv)[(size_t)row * N + col] = f2bf(v);
      }
    }
  }
}

// ---------------------------------------------------------------------------
// ws = s @ atW + atW_b
// ---------------------------------------------------------------------------
__global__ __launch_bounds__(128) void att_ws_kernel(const float* __restrict__ s,
                                                     const float* __restrict__ atW,
                                                     const float* __restrict__ atWb,
                                                     float* __restrict__ ws)
{
  int b = blockIdx.x, a = threadIdx.x;
  float acc = atWb[a];
  for (int k = 0; k < 128; k++) acc += s[b * 128 + k] * atW[k * 128 + a];
  ws[b * 128 + a] = acc;
}

// ---------------------------------------------------------------------------
// Persistent bidirectional-LSTM scan, v2: few fat blocks, narrow barriers.
// m0 (H=256): 4 blocks/dir; m1 (H=128): 2 blocks/dir. 512 thr (8 waves).
// Block bk owns j in [64bk, 64bk+64) -> 256 gate-cols (4 gates x 64 j).
// Wave w: gate g=w>>1, half=w&1 -> 2 n-tiles; all 64 batches (4 m-tiles).
// Weights in registers (B-frags, 64 VGPR). h exchanged via IC with RELAXED
// agent-scope atomics (per-access coherent; no L2-maintenance fences).
// Gate combine via 33KB LDS transpose, 2 batch-passes, XOR bank swizzle.
// Cell state c in registers. Per-scan-dir counter barrier (4 or 2 parties).
// ---------------------------------------------------------------------------
template<int H, int NBLK>
__device__ __forceinline__ void scan2(const short* __restrict__ xg,
                                      const float* __restrict__ Wh,
                                      short* __restrict__ hall,
                                      int* __restrict__ ctr,
                                      int bk, int dir, float* gl)
{
  constexpr int C = 2 * H, H4 = 4 * H, KB = H / 32;
  const int tid = threadIdx.x, lane = tid & 63, w = tid >> 6;
  const int g = w >> 1, half = w & 1;
  const int n16 = lane & 15, rg = lane >> 4;
  const int j0g = bk * 64;
  const int dircol = dir ? H : 0;

  // --- weight fragments bw[nt][kb] (loaded once)
  short8 bw[2][KB];
#pragma unroll
  for (int nt = 0; nt < 2; nt++) {
    int colg = g * H + j0g + half * 32 + nt * 16 + n16;
#pragma unroll
    for (int kb = 0; kb < KB; kb++)
#pragma unroll
      for (int e = 0; e < 8; e++)
        bw[nt][kb][e] = f2bf(Wh[(size_t)(kb * 32 + rg * 8 + e) * H4 + colg]);
  }

  const int cb = tid >> 4;     // combine row (0..31), jq = j quad
  const int jq = tid & 15;
  float cst[2][4];
#pragma unroll
  for (int p = 0; p < 2; p++)
#pragma unroll
    for (int jj = 0; jj < 4; jj++) cst[p][jj] = 0.f;

  short xgr[4][2][4];
  auto fetch_xg = [&](int tt) {
#pragma unroll
    for (int mt = 0; mt < 4; mt++)
#pragma unroll
      for (int nt = 0; nt < 2; nt++) {
        int colg = g * H + j0g + half * 32 + nt * 16 + n16;
#pragma unroll
        for (int q = 0; q < 4; q++) {
          int batch = mt * 16 + rg * 4 + q;
          xgr[mt][nt][q] = xg[(size_t)(tt * 64 + batch) * H4 + colg];
        }
      }
  };

  int t = dir ? 511 : 0;
  fetch_xg(t);

  for (int s = 0; s < 512; s++) {
    t = dir ? 511 - s : s;
    f32x4 acc[4][2];
#pragma unroll
    for (int mt = 0; mt < 4; mt++)
#pragma unroll
      for (int nt = 0; nt < 2; nt++)
#pragma unroll
        for (int q = 0; q < 4; q++) acc[mt][nt][q] = 0.f;

    if (s > 0) {
      int tp = dir ? t + 1 : t - 1;
#pragma unroll
      for (int mt = 0; mt < 4; mt++) {
        U8 u[KB];
        const unsigned long long* hb = (const unsigned long long*)
            (hall + ((size_t)tp * 64 + mt * 16 + n16) * C + dircol);
#pragma unroll
        for (int kb = 0; kb < KB; kb++) {
          int bofs = (kb * 32 + rg * 8) >> 2;
          u[kb].u[0] = __hip_atomic_load(hb + bofs,     __ATOMIC_RELAXED, __HIP_MEMORY_SCOPE_AGENT);
          u[kb].u[1] = __hip_atomic_load(hb + bofs + 1, __ATOMIC_RELAXED, __HIP_MEMORY_SCOPE_AGENT);
        }
#pragma unroll
        for (int kb = 0; kb < KB; kb++) {
          acc[mt][0] = __builtin_amdgcn_mfma_f32_16x16x32_bf16(u[kb].s, bw[0][kb], acc[mt][0], 0, 0, 0);
          acc[mt][1] = __builtin_amdgcn_mfma_f32_16x16x32_bf16(u[kb].s, bw[1][kb], acc[mt][1], 0, 0, 0);
        }
      }
    }

    // --- gate transpose + combine, 2 batch-passes of 32
#pragma unroll
    for (int p = 0; p < 2; p++) {
#pragma unroll
      for (int mt = 2 * p; mt < 2 * p + 2; mt++)
#pragma unroll
        for (int nt = 0; nt < 2; nt++) {
          int col = g * 64 + half * 32 + nt * 16 + n16;
#pragma unroll
          for (int q = 0; q < 4; q++) {
            int bl = (mt & 1) * 16 + rg * 4 + q;
            gl[bl * 260 + (col ^ ((bl & 7) << 2))] = acc[mt][nt][q] + bf2f(xgr[mt][nt][q]);
          }
        }
      __syncthreads();
      {
        int b = p * 32 + cb;
        int sw = (cb & 7) << 2;
        f32x4 ga = *(f32x4*)&gl[cb * 260 + ((0 * 64 + jq * 4) ^ sw)];
        f32x4 gi = *(f32x4*)&gl[cb * 260 + ((1 * 64 + jq * 4) ^ sw)];
        f32x4 gf = *(f32x4*)&gl[cb * 260 + ((2 * 64 + jq * 4) ^ sw)];
        f32x4 go = *(f32x4*)&gl[cb * 260 + ((3 * 64 + jq * 4) ^ sw)];
        unsigned long long pk = 0;
#pragma unroll
        for (int jj = 0; jj < 4; jj++) {
          float cc = ftanh(ga[jj]) * sigm(gi[jj]) + cst[p][jj] * sigm(gf[jj]);
          cst[p][jj] = cc;
          unsigned long long hh = (unsigned short)f2bf(ftanh(cc) * sigm(go[jj]));
          pk |= hh << (16 * jj);
        }
        __hip_atomic_store((unsigned long long*)(hall + ((size_t)t * 64 + b) * C + dircol + j0g + jq * 4),
                           pk, __ATOMIC_RELAXED, __HIP_MEMORY_SCOPE_AGENT);
      }
      __syncthreads();
    }

    if (s < 511) {
      if (tid == 0)
        __hip_atomic_fetch_add(ctr, 1, __ATOMIC_RELAXED, __HIP_MEMORY_SCOPE_AGENT);
      fetch_xg(dir ? t - 1 : t + 1);     // overlaps the spin
      if (tid == 0) {
        int target = (s + 1) * NBLK;
        while (__hip_atomic_load(ctr, __ATOMIC_RELAXED, __HIP_MEMORY_SCOPE_AGENT) < target)
          __builtin_amdgcn_s_sleep(1);
      }
      __syncthreads();
    }
  }
}

__global__ __launch_bounds__(512, 2) void lstm_persistent(
    const short* __restrict__ xgf0, const short* __restrict__ xgb0,
    const short* __restrict__ xgf1, const short* __restrict__ xgb1,
    const float* __restrict__ fh0, const float* __restrict__ bh0,
    const float* __restrict__ fh1, const float* __restrict__ bh1,
    short* __restrict__ hall0, short* __restrict__ hall1, int* __restrict__ bar)
{
  __shared__ float gl[32 * 260];
  int bx = blockIdx.x;
  if (bx < 8) {
    int dir = bx >> 2, bk = bx & 3;
    scan2<256, 4>(dir ? xgb0 : xgf0, dir ? bh0 : fh0, hall0,
                  bar + dir * 64, bk, dir, gl);
  } else {
    int r = bx - 8, dir = r >> 1, bk = r & 1;
    scan2<128, 2>(dir ? xgb1 : xgf1, dir ? bh1 : fh1, hall1,
                  bar + 128 + dir * 64, bk, dir, gl);
  }
}

// ---------------------------------------------------------------------------
// logits[r] = tanh(vh[r,:] + ws[b,:]) . atw + atw_b
// ---------------------------------------------------------------------------
__global__ __launch_bounds__(256) void logits_kernel(const float* __restrict__ vh,
                                                     const float* __restrict__ ws,
                                                     const float* __restrict__ atw,
                                                     const float* __restrict__ atwb,
                                                     float* __restrict__ lg)
{
  int wid  = (int)((blockIdx.x * 256 + threadIdx.x) >> 6);
  int lane = threadIdx.x & 63;
  if (wid >= 32768) return;
  int b = wid & 63;
  float x0 = vh[(size_t)wid * 128 + lane]      + ws[b * 128 + lane];
  float x1 = vh[(size_t)wid * 128 + 64 + lane] + ws[b * 128 + 64 + lane];
  float v = ftanh(x0) * atw[lane] + ftanh(x1) * atw[64 + lane];
  for (int off = 32; off; off >>= 1) v += __shfl_down(v, off);
  if (lane == 0) lg[wid] = v + atwb[0];
}

// ---------------------------------------------------------------------------
// Per-batch softmax over T + context
// ---------------------------------------------------------------------------
__global__ __launch_bounds__(256) void softmax_ctx(const float* __restrict__ lg,
                                                   const short* __restrict__ hall,
                                                   float* __restrict__ ctx, int C)
{
  int b = blockIdx.x, tid = threadIdx.x, lane = tid & 63, wv = tid >> 6;
  __shared__ float ebuf[512];
  __shared__ float red[8];
  float l0 = lg[tid * 64 + b];
  float l1 = lg[(tid + 256) * 64 + b];
  float m = fmaxf(l0, l1);
  for (int o = 32; o; o >>= 1) m = fmaxf(m, __shfl_xor(m, o));
  if (lane == 0) red[wv] = m;
  __syncthreads();
  m = fmaxf(fmaxf(red[0], red[1]), fmaxf(red[2], red[3]));
  float e0 = __expf(l0 - m), e1 = __expf(l1 - m);
  ebuf[tid] = e0; ebuf[tid + 256] = e1;
  float sm = e0 + e1;
  for (int o = 32; o; o >>= 1) sm += __shfl_xor(sm, o);
  if (lane == 0) red[4 + wv] = sm;
  __syncthreads();
  sm = red[4] + red[5] + red[6] + red[7];
  float inv = 1.f / (sm * 512.f);
  for (int c = tid; c < C; c += 256) {
    float acc = 0.f;
    const short* hp = hall + (size_t)b * C + c;
    for (int t = 0; t < 512; t++) acc += ebuf[t] * bf2f(hp[(size_t)t * 64 * C]);
    ctx[b * C + c] = acc * inv;
  }
}

// ---------------------------------------------------------------------------
__global__ __launch_bounds__(256) void final_kernel(const float* __restrict__ ctx0,
                                                    const float* __restrict__ ctx1,
                                                    const float* __restrict__ w0,
                                                    const float* __restrict__ b0,
                                                    const float* __restrict__ w1,
                                                    const float* __restrict__ b1,
                                                    float* __restrict__ out)
{
  int b = blockIdx.x, o = threadIdx.x;
  float acc = b0[o] + b1[o];
  for (int c = 0; c < 512; c++) acc += ctx0[b * 512 + c] * w0[c * 256 + o];
  for (int c = 0; c < 256; c++) acc += ctx1[b * 256 + c] * w1[c * 256 + o];
  out[b * 256 + o] = ftanh(acc);
}

// ---------------------------------------------------------------------------
extern "C" void kernel_launch(void* const* d_in, const int* in_sizes, int n_in,
                              void* d_out, int out_size, void* d_ws, size_t ws_size,
                              hipStream_t stream)
{
  const float* x0    = (const float*)d_in[0];
  const float* x1    = (const float*)d_in[1];
  const float* sIn   = (const float*)d_in[2];
  const float* emb_w0 = (const float*)d_in[3];  const float* emb_b0 = (const float*)d_in[4];
  const float* fx_w0  = (const float*)d_in[5];  const float* fx_b0  = (const float*)d_in[6];
  const float* fh_w0  = (const float*)d_in[7];
  const float* bx_w0  = (const float*)d_in[8];  const float* bx_b0  = (const float*)d_in[9];
  const float* bh_w0  = (const float*)d_in[10];
  const float* atV_w0 = (const float*)d_in[11]; const float* atV_b0 = (const float*)d_in[12];
  const float* atW_w0 = (const float*)d_in[13]; const float* atW_b0 = (const float*)d_in[14];
  const float* atw_w0 = (const float*)d_in[15]; const float* atw_b0 = (const float*)d_in[16];
  const float* lgd_w0 = (const float*)d_in[17]; const float* lgd_b0 = (const float*)d_in[18];
  const float* emb_w1 = (const float*)d_in[19]; const float* emb_b1 = (const float*)d_in[20];
  const float* fx_w1  = (const float*)d_in[21]; const float* fx_b1  = (const float*)d_in[22];
  const float* fh_w1  = (const float*)d_in[23];
  const float* bx_w1  = (const float*)d_in[24]; const float* bx_b1  = (const float*)d_in[25];
  const float* bh_w1  = (const float*)d_in[26];
  const float* atV_w1 = (const float*)d_in[27]; const float* atV_b1 = (const float*)d_in[28];
  const float* atW_w1 = (const float*)d_in[29]; const float* atW_b1 = (const float*)d_in[30];
  const float* atw_w1 = (const float*)d_in[31]; const float* atw_b1 = (const float*)d_in[32];
  const float* lgd_w1 = (const float*)d_in[33]; const float* lgd_b1 = (const float*)d_in[34];
  float* out = (float*)d_out;

  char* wp = (char*)d_ws;
  auto alloc = [&](size_t bytes) -> void* {
    void* p = wp; wp += (bytes + 255) & ~(size_t)255; return p;
  };
  int*   bar   = (int*)alloc(1024);                 // 4 barrier counters, 256B apart
  short* h0_0  = (short*)alloc(32768ull * 512 * 2);
  short* h0_1  = (short*)alloc(32768ull * 128 * 2);
  short* xgf0  = (short*)alloc(32768ull * 1024 * 2);
  short* xgb0  = (short*)alloc(32768ull * 1024 * 2);
  short* xgf1  = (short*)alloc(32768ull * 512 * 2);
  short* xgb1  = (short*)alloc(32768ull * 512 * 2);
  short* hall0 = (short*)alloc(32768ull * 512 * 2);
  short* hall1 = (short*)alloc(32768ull * 256 * 2);
  float* vh0   = (float*)alloc(32768ull * 128 * 4);
  float* vh1   = (float*)alloc(32768ull * 128 * 4);
  float* wsb0  = (float*)alloc(64 * 128 * 4);
  float* wsb1  = (float*)alloc(64 * 128 * 4);
  float* lg0   = (float*)alloc(32768 * 4);
  float* lg1   = (float*)alloc(32768 * 4);
  float* ctx0  = (float*)alloc(64 * 512 * 4);
  float* ctx1  = (float*)alloc(64 * 256 * 4);

  // embeddings (f32 in, bf16 out)
  gemm_bias<1, 0><<<dim3(4, 256), 256, 0, stream>>>(x0, emb_w0, emb_b0, h0_0, 32768, 512, 2048);
  gemm_bias<1, 0><<<dim3(1, 256), 256, 0, stream>>>(x1, emb_w1, emb_b1, h0_1, 32768, 128, 128);
  // input projections (bf16 in, bf16 out)
  gemm_bias<0, 0><<<dim3(8, 256), 256, 0, stream>>>(h0_0, fx_w0, fx_b0, xgf0, 32768, 1024, 512);
  gemm_bias<0, 0><<<dim3(8, 256), 256, 0, stream>>>(h0_0, bx_w0, bx_b0, xgb0, 32768, 1024, 512);
  gemm_bias<0, 0><<<dim3(4, 256), 256, 0, stream>>>(h0_1, fx_w1, fx_b1, xgf1, 32768, 512, 128);
  gemm_bias<0, 0><<<dim3(4, 256), 256, 0, stream>>>(h0_1, bx_w1, bx_b1, xgb1, 32768, 512, 128);
  // attention s-projection
  att_ws_kernel<<<64, 128, 0, stream>>>(sIn, atW_w0, atW_b0, wsb0);
  att_ws_kernel<<<64, 128, 0, stream>>>(sIn, atW_w1, atW_b1, wsb1);

  // persistent bidirectional LSTM scans (one dispatch, 512 internal steps)
  hipMemsetAsync(bar, 0, 1024, stream);
  lstm_persistent<<<12, 512, 0, stream>>>(xgf0, xgb0, xgf1, xgb1,
                                          fh_w0, bh_w0, fh_w1, bh_w1,
                                          hall0, hall1, bar);

  // attention
  gemm_bias<0, 1><<<dim3(1, 256), 256, 0, stream>>>(hall0, atV_w0, atV_b0, vh0, 32768, 128, 512);
  gemm_bias<0, 1><<<dim3(1, 256), 256, 0, stream>>>(hall1, atV_w1, atV_b1, vh1, 32768, 128, 256);
  logits_kernel<<<8192, 256, 0, stream>>>(vh0, wsb0, atw_w0, atw_b0, lg0);
  logits_kernel<<<8192, 256, 0, stream>>>(vh1, wsb1, atw_w1, atw_b1, lg1);
  softmax_ctx<<<64, 256, 0, stream>>>(lg0, hall0, ctx0, 512);
  softmax_ctx<<<64, 256, 0, stream>>>(lg1, hall1, ctx1, 256);
  final_kernel<<<64, 256, 0, stream>>>(ctx0, ctx1, lgd_w0, lgd_b0, lgd_w1, lgd_b1, out);
}

// Round 5
// 5456.109 us; speedup vs baseline: 1.9079x; 1.9079x over previous
//
#include <hip/hip_runtime.h>

typedef __attribute__((ext_vector_type(4))) float  f32x4;
typedef __attribute__((ext_vector_type(8))) short  short8;
typedef __attribute__((ext_vector_type(4))) short  short4v;

__device__ __forceinline__ float bf2f(short s){
  unsigned u = ((unsigned)(unsigned short)s) << 16;
  float f; __builtin_memcpy(&f, &u, 4); return f;
}
__device__ __forceinline__ short f2bf(float x){
  unsigned u; __builtin_memcpy(&u, &x, 4);
  u = (u + 0x7fffu + ((u >> 16) & 1u)) >> 16;
  return (short)u;
}
__device__ __forceinline__ float sigm(float x){ return 1.f / (1.f + __expf(-x)); }
__device__ __forceinline__ float ftanh(float x){ return 1.f - 2.f / (__expf(2.f * x) + 1.f); }

// L2-bypassing (agent-coherent) 16B load/store — pipelined, unlike per-element
// HIP atomics which the compiler serializes (R3/R4 post-mortem).
__device__ __forceinline__ short8 ld_b128_sc1(const short* p){
  short8 r;
  asm volatile("global_load_dwordx4 %0, %1, off sc1" : "=&v"(r) : "v"(p) : "memory");
  return r;
}
__device__ __forceinline__ void st_b128_sc1(short* p, short8 v){
  asm volatile("global_store_dwordx4 %0, %1, off sc1" :: "v"(p), "v"(v) : "memory");
}
__device__ __forceinline__ void wait_vm0(){
  asm volatile("s_waitcnt vmcnt(0)" ::: "memory");
  __builtin_amdgcn_sched_barrier(0);
}

// ---------------------------------------------------------------------------
// Generic bf16-MFMA GEMM: C[M,N] = A[M,K] * B[K,N] + bias[N]
// ---------------------------------------------------------------------------
template<int AF32, int OF32>
__global__ __launch_bounds__(256) void gemm_bias(const void* __restrict__ Av,
                                                 const float* __restrict__ B,
                                                 const float* __restrict__ bias,
                                                 void* __restrict__ Cv,
                                                 int M, int N, int K)
{
  __shared__ __align__(16) short As[128 * 40];
  __shared__ __align__(16) short Bs[128 * 40];
  int tid  = threadIdx.x;
  int col0 = blockIdx.x * 128, row0 = blockIdx.y * 128;
  int lane = tid & 63, wave = tid >> 6;
  int wm = (wave >> 1) * 64, wn = (wave & 1) * 64;

  f32x4 acc[4][4];
  for (int mi = 0; mi < 4; mi++)
    for (int ni = 0; ni < 4; ni++)
      for (int q = 0; q < 4; q++) acc[mi][ni][q] = 0.f;

  for (int kt = 0; kt < K; kt += 32) {
    __syncthreads();
    if (AF32) {
      const float* A = (const float*)Av;
      for (int i = 0; i < 4; i++) {
        int idx = tid + i * 256;
        int r = idx >> 3, c4 = (idx & 7) << 2;
        f32x4 v = *(const f32x4*)(A + (size_t)(row0 + r) * K + kt + c4);
        short4v o;
        for (int q = 0; q < 4; q++) o[q] = f2bf(v[q]);
        *(short4v*)&As[r * 40 + c4] = o;
      }
    } else {
      const short* A = (const short*)Av;
      for (int i = 0; i < 2; i++) {
        int idx = tid + i * 256;
        int r = idx >> 2, c8 = (idx & 3) << 3;
        short8 v = *(const short8*)(A + (size_t)(row0 + r) * K + kt + c8);
        *(short8*)&As[r * 40 + c8] = v;
      }
    }
    for (int i = 0; i < 4; i++) {
      int idx = tid + i * 256;
      int kr = idx >> 5, c4 = (idx & 31) << 2;
      f32x4 v = *(const f32x4*)(B + (size_t)(kt + kr) * N + col0 + c4);
      for (int e = 0; e < 4; e++) Bs[(c4 + e) * 40 + kr] = f2bf(v[e]);
    }
    __syncthreads();

    int fr = lane & 15, fo = (lane >> 4) << 3;
    short8 af[4], bfr[4];
    for (int mi = 0; mi < 4; mi++) af[mi]  = *(short8*)&As[(wm + mi * 16 + fr) * 40 + fo];
    for (int ni = 0; ni < 4; ni++) bfr[ni] = *(short8*)&Bs[(wn + ni * 16 + fr) * 40 + fo];
    for (int mi = 0; mi < 4; mi++)
      for (int ni = 0; ni < 4; ni++)
        acc[mi][ni] = __builtin_amdgcn_mfma_f32_16x16x32_bf16(af[mi], bfr[ni], acc[mi][ni], 0, 0, 0);
  }

  int efr = lane & 15, efrow = (lane >> 4) << 2;
  for (int ni = 0; ni < 4; ni++) {
    int col = col0 + wn + ni * 16 + efr;
    float bv = bias[col];
    for (int mi = 0; mi < 4; mi++) {
      for (int q = 0; q < 4; q++) {
        int row = row0 + wm + mi * 16 + efrow + q;
        float v = acc[mi][ni][q] + bv;
        if (OF32) ((float*)Cv)[(size_t)row * N + col] = v;
        else      ((short*)Cv)[(size_t)row * N + col] = f2bf(v);
      }
    }
  }
}

// ---------------------------------------------------------------------------
// ws = s @ atW + atW_b
// ---------------------------------------------------------------------------
__global__ __launch_bounds__(128) void att_ws_kernel(const float* __restrict__ s,
                                                     const float* __restrict__ atW,
                                                     const float* __restrict__ atWb,
                                                     float* __restrict__ ws)
{
  int b = blockIdx.x, a = threadIdx.x;
  float acc = atWb[a];
  for (int k = 0; k < 128; k++) acc += s[b * 128 + k] * atW[k * 128 + a];
  ws[b * 128 + a] = acc;
}

// ---------------------------------------------------------------------------
// m0 scan (H=256): 4 blocks/dir x 512 thr. Per step: cooperative LDS stage of
// full h_prev (sc1 vector loads), MFMA from LDS, gate transpose via gl,
// epilogue with c in registers, packed sc1 h store, 4-party counter barrier.
// ---------------------------------------------------------------------------
__device__ __forceinline__ void scan_m0(const short* __restrict__ xg,
                                        const float* __restrict__ Wh,
                                        short* __restrict__ hall,
                                        int* __restrict__ ctr,
                                        int bk, int dir, char* smem)
{
  constexpr int H = 256, C = 512, H4 = 1024, KB = 8;
  float* gl = (float*)smem;                 // [64][257] f32 (65792 B)
  char*  hsb = smem + 65792;                // 64 rows x 512 B (swizzled h)
  const int tid = threadIdx.x, lane = tid & 63, w = tid >> 6;
  const int g = w >> 1, half = w & 1;
  const int n16 = lane & 15, rg = lane >> 4;
  const int j0g = bk * 64, dircol = dir ? H : 0;

  // weight fragments (once)
  short8 bw[2][KB];
#pragma unroll
  for (int nt = 0; nt < 2; nt++) {
    int colg = g * H + j0g + half * 32 + nt * 16 + n16;
#pragma unroll
    for (int kb = 0; kb < KB; kb++)
#pragma unroll
      for (int e = 0; e < 8; e++)
        bw[nt][kb][e] = f2bf(Wh[(size_t)(kb * 32 + rg * 8 + e) * H4 + colg]);
  }

  const int eb = tid & 63, jq = tid >> 6;   // epilogue/stage mapping
  float cst[8];
#pragma unroll
  for (int jj = 0; jj < 8; jj++) cst[jj] = 0.f;

  for (int s = 0; s < 512; s++) {
    int t = dir ? 511 - s : s;
    // xg prefetch (normal loads; compiler-tracked)
    short8 xgp[4];
#pragma unroll
    for (int gg = 0; gg < 4; gg++)
      xgp[gg] = *(const short8*)(xg + (size_t)(t * 64 + eb) * H4 + gg * H + j0g + jq * 8);

    // cooperative stage of full h_prev into LDS (XOR-swizzled 16B blocks)
    if (s > 0) {
      int tp = dir ? t + 1 : t - 1;
      const short* hb = hall + (size_t)(tp * 64 + eb) * C + dircol;
      short8 v0 = ld_b128_sc1(hb + (jq * 4 + 0) * 8);
      short8 v1 = ld_b128_sc1(hb + (jq * 4 + 1) * 8);
      short8 v2 = ld_b128_sc1(hb + (jq * 4 + 2) * 8);
      short8 v3 = ld_b128_sc1(hb + (jq * 4 + 3) * 8);
      wait_vm0();
      *(short8*)(hsb + eb * 512 + (((jq * 4 + 0) ^ (eb & 7)) << 4)) = v0;
      *(short8*)(hsb + eb * 512 + (((jq * 4 + 1) ^ (eb & 7)) << 4)) = v1;
      *(short8*)(hsb + eb * 512 + (((jq * 4 + 2) ^ (eb & 7)) << 4)) = v2;
      *(short8*)(hsb + eb * 512 + (((jq * 4 + 3) ^ (eb & 7)) << 4)) = v3;
    }
    __syncthreads();

    // MFMA: h_prev (LDS) @ Wh (regs)
    f32x4 acc[4][2];
#pragma unroll
    for (int mt = 0; mt < 4; mt++)
#pragma unroll
      for (int nt = 0; nt < 2; nt++)
#pragma unroll
        for (int q = 0; q < 4; q++) acc[mt][nt][q] = 0.f;
    if (s > 0) {
#pragma unroll
      for (int kb = 0; kb < KB; kb++) {
        short8 a[4];
#pragma unroll
        for (int mt = 0; mt < 4; mt++) {
          int row = mt * 16 + n16;
          a[mt] = *(const short8*)(hsb + row * 512 + (((kb * 4 + rg) ^ (row & 7)) << 4));
        }
#pragma unroll
        for (int mt = 0; mt < 4; mt++) {
          acc[mt][0] = __builtin_amdgcn_mfma_f32_16x16x32_bf16(a[mt], bw[0][kb], acc[mt][0], 0, 0, 0);
          acc[mt][1] = __builtin_amdgcn_mfma_f32_16x16x32_bf16(a[mt], bw[1][kb], acc[mt][1], 0, 0, 0);
        }
      }
    }

    // write gates to gl[batch][col], col = g*64 + j
#pragma unroll
    for (int mt = 0; mt < 4; mt++)
#pragma unroll
      for (int nt = 0; nt < 2; nt++)
#pragma unroll
        for (int q = 0; q < 4; q++)
          gl[(mt * 16 + rg * 4 + q) * 257 + g * 64 + half * 32 + nt * 16 + n16] = acc[mt][nt][q];
    __syncthreads();

    // epilogue: thread -> (batch eb, j8 = jq*8), c in registers
    {
      const float* gb = gl + eb * 257 + jq * 8;
      short8 h8;
#pragma unroll
      for (int jj = 0; jj < 8; jj++) {
        float a_ = gb[0 * 64 + jj] + bf2f(xgp[0][jj]);
        float i_ = gb[1 * 64 + jj] + bf2f(xgp[1][jj]);
        float f_ = gb[2 * 64 + jj] + bf2f(xgp[2][jj]);
        float o_ = gb[3 * 64 + jj] + bf2f(xgp[3][jj]);
        float cc = ftanh(a_) * sigm(i_) + cst[jj] * sigm(f_);
        cst[jj] = cc;
        h8[jj] = f2bf(ftanh(cc) * sigm(o_));
      }
      st_b128_sc1(hall + (size_t)(t * 64 + eb) * C + dircol + j0g + jq * 8, h8);
    }

    if (s < 511) {
      wait_vm0();            // h stores ACKed (compiler can't see asm stores)
      __syncthreads();
      if (tid == 0) {
        __hip_atomic_fetch_add(ctr, 1, __ATOMIC_RELAXED, __HIP_MEMORY_SCOPE_AGENT);
        int target = (s + 1) * 4;
        while (__hip_atomic_load(ctr, __ATOMIC_RELAXED, __HIP_MEMORY_SCOPE_AGENT) < target) {}
      }
      __syncthreads();
    }
  }
}

// ---------------------------------------------------------------------------
// m1 scan (H=128): ONE block per direction. Weights in registers, h in LDS —
// zero cross-block traffic, zero barrier. Off the critical path.
// ---------------------------------------------------------------------------
__device__ __forceinline__ void scan_m1(const short* __restrict__ xg,
                                        const float* __restrict__ Wh,
                                        short* __restrict__ hall,
                                        int dir, char* smem)
{
  constexpr int H = 128, C = 256, H4 = 512, KB = 4;
  float* gl = (float*)smem;                 // [64][513] f32 (131328 B)
  char*  hsb = smem + 131328;               // 64 rows x 256 B (swizzled h)
  const int tid = threadIdx.x, lane = tid & 63, w = tid >> 6;
  const int n16 = lane & 15, rg = lane >> 4;
  const int dircol = dir ? H : 0;

  short8 bw[4][KB];
#pragma unroll
  for (int nt = 0; nt < 4; nt++) {
    int colg = w * 64 + nt * 16 + n16;      // gatecol 0..511
#pragma unroll
    for (int kb = 0; kb < KB; kb++)
#pragma unroll
      for (int e = 0; e < 8; e++)
        bw[nt][kb][e] = f2bf(Wh[(size_t)(kb * 32 + rg * 8 + e) * H4 + colg]);
  }

  const int eb = tid & 63, jh = tid >> 6;   // 16 cells: j16 = jh*16
  float cst[16];
#pragma unroll
  for (int jj = 0; jj < 16; jj++) cst[jj] = 0.f;

  for (int s = 0; s < 512; s++) {
    int t = dir ? 511 - s : s;
    short8 xgp[8];
#pragma unroll
    for (int gg = 0; gg < 4; gg++)
#pragma unroll
      for (int i = 0; i < 2; i++)
        xgp[gg * 2 + i] = *(const short8*)(xg + (size_t)(t * 64 + eb) * H4 + gg * H + jh * 16 + i * 8);
    __syncthreads();   // hs ready (prev epilogue), gl free

    f32x4 acc[4][4];
#pragma unroll
    for (int mt = 0; mt < 4; mt++)
#pragma unroll
      for (int nt = 0; nt < 4; nt++)
#pragma unroll
        for (int q = 0; q < 4; q++) acc[mt][nt][q] = 0.f;
    if (s > 0) {
#pragma unroll
      for (int kb = 0; kb < KB; kb++) {
        short8 a[4];
#pragma unroll
        for (int mt = 0; mt < 4; mt++) {
          int row = mt * 16 + n16;
          a[mt] = *(const short8*)(hsb + row * 256 + (((kb * 4 + rg) ^ (row & 7)) << 4));
        }
#pragma unroll
        for (int mt = 0; mt < 4; mt++)
#pragma unroll
          for (int nt = 0; nt < 4; nt++)
            acc[mt][nt] = __builtin_amdgcn_mfma_f32_16x16x32_bf16(a[mt], bw[nt][kb], acc[mt][nt], 0, 0, 0);
      }
    }
#pragma unroll
    for (int mt = 0; mt < 4; mt++)
#pragma unroll
      for (int nt = 0; nt < 4; nt++)
#pragma unroll
        for (int q = 0; q < 4; q++)
          gl[(mt * 16 + rg * 4 + q) * 513 + w * 64 + nt * 16 + n16] = acc[mt][nt][q];
    __syncthreads();

    // epilogue: 16 cells (batch eb, j = jh*16 + jx)
#pragma unroll
    for (int i = 0; i < 2; i++) {
      short8 h8;
#pragma unroll
      for (int jj = 0; jj < 8; jj++) {
        int jx = i * 8 + jj;
        int col = jh * 16 + jx;
        float a_ = gl[eb * 513 + 0 * 128 + col] + bf2f(xgp[0 * 2 + i][jj]);
        float i_ = gl[eb * 513 + 1 * 128 + col] + bf2f(xgp[1 * 2 + i][jj]);
        float f_ = gl[eb * 513 + 2 * 128 + col] + bf2f(xgp[2 * 2 + i][jj]);
        float o_ = gl[eb * 513 + 3 * 128 + col] + bf2f(xgp[3 * 2 + i][jj]);
        float cc = ftanh(a_) * sigm(i_) + cst[jx] * sigm(f_);
        cst[jx] = cc;
        h8[jj] = f2bf(ftanh(cc) * sigm(o_));
      }
      *(short8*)(hsb + eb * 256 + (((jh * 2 + i) ^ (eb & 7)) << 4)) = h8;
      *(short8*)(hall + (size_t)(t * 64 + eb) * C + dircol + jh * 16 + i * 8) = h8;
    }
  }
}

__global__ __launch_bounds__(512, 1) void lstm_persistent(
    const short* __restrict__ xgf0, const short* __restrict__ xgb0,
    const short* __restrict__ xgf1, const short* __restrict__ xgb1,
    const float* __restrict__ fh0, const float* __restrict__ bh0,
    const float* __restrict__ fh1, const float* __restrict__ bh1,
    short* __restrict__ hall0, short* __restrict__ hall1, int* __restrict__ bar)
{
  extern __shared__ char smem[];
  int bx = blockIdx.x;
  if (bx < 8) {
    int dir = bx >> 2, bk = bx & 3;
    scan_m0(dir ? xgb0 : xgf0, dir ? bh0 : fh0, hall0, bar + dir * 64, bk, dir, smem);
  } else {
    int dir = bx - 8;
    scan_m1(dir ? xgb1 : xgf1, dir ? bh1 : fh1, hall1, dir, smem);
  }
}

// ---------------------------------------------------------------------------
// logits[r] = tanh(vh[r,:] + ws[b,:]) . atw + atw_b
// ---------------------------------------------------------------------------
__global__ __launch_bounds__(256) void logits_kernel(const float* __restrict__ vh,
                                                     const float* __restrict__ ws,
                                                     const float* __restrict__ atw,
                                                     const float* __restrict__ atwb,
                                                     float* __restrict__ lg)
{
  int wid  = (int)((blockIdx.x * 256 + threadIdx.x) >> 6);
  int lane = threadIdx.x & 63;
  if (wid >= 32768) return;
  int b = wid & 63;
  float x0 = vh[(size_t)wid * 128 + lane]      + ws[b * 128 + lane];
  float x1 = vh[(size_t)wid * 128 + 64 + lane] + ws[b * 128 + 64 + lane];
  float v = ftanh(x0) * atw[lane] + ftanh(x1) * atw[64 + lane];
  for (int off = 32; off; off >>= 1) v += __shfl_down(v, off);
  if (lane == 0) lg[wid] = v + atwb[0];
}

// ---------------------------------------------------------------------------
// Per-batch softmax over T + context
// ---------------------------------------------------------------------------
__global__ __launch_bounds__(256) void softmax_ctx(const float* __restrict__ lg,
                                                   const short* __restrict__ hall,
                                                   float* __restrict__ ctx, int C)
{
  int b = blockIdx.x, tid = threadIdx.x, lane = tid & 63, wv = tid >> 6;
  __shared__ float ebuf[512];
  __shared__ float red[8];
  float l0 = lg[tid * 64 + b];
  float l1 = lg[(tid + 256) * 64 + b];
  float m = fmaxf(l0, l1);
  for (int o = 32; o; o >>= 1) m = fmaxf(m, __shfl_xor(m, o));
  if (lane == 0) red[wv] = m;
  __syncthreads();
  m = fmaxf(fmaxf(red[0], red[1]), fmaxf(red[2], red[3]));
  float e0 = __expf(l0 - m), e1 = __expf(l1 - m);
  ebuf[tid] = e0; ebuf[tid + 256] = e1;
  float sm = e0 + e1;
  for (int o = 32; o; o >>= 1) sm += __shfl_xor(sm, o);
  if (lane == 0) red[4 + wv] = sm;
  __syncthreads();
  sm = red[4] + red[5] + red[6] + red[7];
  float inv = 1.f / (sm * 512.f);
  for (int c = tid; c < C; c += 256) {
    float acc = 0.f;
    const short* hp = hall + (size_t)b * C + c;
    for (int t = 0; t < 512; t++) acc += ebuf[t] * bf2f(hp[(size_t)t * 64 * C]);
    ctx[b * C + c] = acc * inv;
  }
}

// ---------------------------------------------------------------------------
__global__ __launch_bounds__(256) void final_kernel(const float* __restrict__ ctx0,
                                                    const float* __restrict__ ctx1,
                                                    const float* __restrict__ w0,
                                                    const float* __restrict__ b0,
                                                    const float* __restrict__ w1,
                                                    const float* __restrict__ b1,
                                                    float* __restrict__ out)
{
  int b = blockIdx.x, o = threadIdx.x;
  float acc = b0[o] + b1[o];
  for (int c = 0; c < 512; c++) acc += ctx0[b * 512 + c] * w0[c * 256 + o];
  for (int c = 0; c < 256; c++) acc += ctx1[b * 256 + c] * w1[c * 256 + o];
  out[b * 256 + o] = ftanh(acc);
}

// ---------------------------------------------------------------------------
extern "C" void kernel_launch(void* const* d_in, const int* in_sizes, int n_in,
                              void* d_out, int out_size, void* d_ws, size_t ws_size,
                              hipStream_t stream)
{
  const float* x0    = (const float*)d_in[0];
  const float* x1    = (const float*)d_in[1];
  const float* sIn   = (const float*)d_in[2];
  const float* emb_w0 = (const float*)d_in[3];  const float* emb_b0 = (const float*)d_in[4];
  const float* fx_w0  = (const float*)d_in[5];  const float* fx_b0  = (const float*)d_in[6];
  const float* fh_w0  = (const float*)d_in[7];
  const float* bx_w0  = (const float*)d_in[8];  const float* bx_b0  = (const float*)d_in[9];
  const float* bh_w0  = (const float*)d_in[10];
  const float* atV_w0 = (const float*)d_in[11]; const float* atV_b0 = (const float*)d_in[12];
  const float* atW_w0 = (const float*)d_in[13]; const float* atW_b0 = (const float*)d_in[14];
  const float* atw_w0 = (const float*)d_in[15]; const float* atw_b0 = (const float*)d_in[16];
  const float* lgd_w0 = (const float*)d_in[17]; const float* lgd_b0 = (const float*)d_in[18];
  const float* emb_w1 = (const float*)d_in[19]; const float* emb_b1 = (const float*)d_in[20];
  const float* fx_w1  = (const float*)d_in[21]; const float* fx_b1  = (const float*)d_in[22];
  const float* fh_w1  = (const float*)d_in[23];
  const float* bx_w1  = (const float*)d_in[24]; const float* bx_b1  = (const float*)d_in[25];
  const float* bh_w1  = (const float*)d_in[26];
  const float* atV_w1 = (const float*)d_in[27]; const float* atV_b1 = (const float*)d_in[28];
  const float* atW_w1 = (const float*)d_in[29]; const float* atW_b1 = (const float*)d_in[30];
  const float* atw_w1 = (const float*)d_in[31]; const float* atw_b1 = (const float*)d_in[32];
  const float* lgd_w1 = (const float*)d_in[33]; const float* lgd_b1 = (const float*)d_in[34];
  float* out = (float*)d_out;

  char* wp = (char*)d_ws;
  auto alloc = [&](size_t bytes) -> void* {
    void* p = wp; wp += (bytes + 255) & ~(size_t)255; return p;
  };
  int*   bar   = (int*)alloc(1024);
  short* h0_0  = (short*)alloc(32768ull * 512 * 2);
  short* h0_1  = (short*)alloc(32768ull * 128 * 2);
  short* xgf0  = (short*)alloc(32768ull * 1024 * 2);
  short* xgb0  = (short*)alloc(32768ull * 1024 * 2);
  short* xgf1  = (short*)alloc(32768ull * 512 * 2);
  short* xgb1  = (short*)alloc(32768ull * 512 * 2);
  short* hall0 = (short*)alloc(32768ull * 512 * 2);
  short* hall1 = (short*)alloc(32768ull * 256 * 2);
  float* vh0   = (float*)alloc(32768ull * 128 * 4);
  float* vh1   = (float*)alloc(32768ull * 128 * 4);
  float* wsb0  = (float*)alloc(64 * 128 * 4);
  float* wsb1  = (float*)alloc(64 * 128 * 4);
  float* lg0   = (float*)alloc(32768 * 4);
  float* lg1   = (float*)alloc(32768 * 4);
  float* ctx0  = (float*)alloc(64 * 512 * 4);
  float* ctx1  = (float*)alloc(64 * 256 * 4);

  const int SMEM = 64 * 513 * 4 + 64 * 256;   // 147712 B (m1 layout is the max)
  hipFuncSetAttribute(reinterpret_cast<const void*>(lstm_persistent),
                      hipFuncAttributeMaxDynamicSharedMemorySize, SMEM);

  // embeddings (f32 in, bf16 out)
  gemm_bias<1, 0><<<dim3(4, 256), 256, 0, stream>>>(x0, emb_w0, emb_b0, h0_0, 32768, 512, 2048);
  gemm_bias<1, 0><<<dim3(1, 256), 256, 0, stream>>>(x1, emb_w1, emb_b1, h0_1, 32768, 128, 128);
  // input projections (bf16 in, bf16 out)
  gemm_bias<0, 0><<<dim3(8, 256), 256, 0, stream>>>(h0_0, fx_w0, fx_b0, xgf0, 32768, 1024, 512);
  gemm_bias<0, 0><<<dim3(8, 256), 256, 0, stream>>>(h0_0, bx_w0, bx_b0, xgb0, 32768, 1024, 512);
  gemm_bias<0, 0><<<dim3(4, 256), 256, 0, stream>>>(h0_1, fx_w1, fx_b1, xgf1, 32768, 512, 128);
  gemm_bias<0, 0><<<dim3(4, 256), 256, 0, stream>>>(h0_1, bx_w1, bx_b1, xgb1, 32768, 512, 128);
  // attention s-projection
  att_ws_kernel<<<64, 128, 0, stream>>>(sIn, atW_w0, atW_b0, wsb0);
  att_ws_kernel<<<64, 128, 0, stream>>>(sIn, atW_w1, atW_b1, wsb1);

  // persistent bidirectional LSTM scans
  hipMemsetAsync(bar, 0, 1024, stream);
  lstm_persistent<<<10, 512, SMEM, stream>>>(xgf0, xgb0, xgf1, xgb1,
                                             fh_w0, bh_w0, fh_w1, bh_w1,
                                             hall0, hall1, bar);

  // attention
  gemm_bias<0, 1><<<dim3(1, 256), 256, 0, stream>>>(hall0, atV_w0, atV_b0, vh0, 32768, 128, 512);
  gemm_bias<0, 1><<<dim3(1, 256), 256, 0, stream>>>(hall1, atV_w1, atV_b1, vh1, 32768, 128, 256);
  logits_kernel<<<8192, 256, 0, stream>>>(vh0, wsb0, atw_w0, atw_b0, lg0);
  logits_kernel<<<8192, 256, 0, stream>>>(vh1, wsb1, atw_w1, atw_b1, lg1);
  softmax_ctx<<<64, 256, 0, stream>>>(lg0, hall0, ctx0, 512);
  softmax_ctx<<<64, 256, 0, stream>>>(lg1, hall1, ctx1, 256);
  final_kernel<<<64, 256, 0, stream>>>(ctx0, ctx1, lgd_w0, lgd_b0, lgd_w1, lgd_b1, out);
}

// Round 6
// 5259.629 us; speedup vs baseline: 1.9792x; 1.0374x over previous
//
#include <hip/hip_runtime.h>

typedef __attribute__((ext_vector_type(4))) float  f32x4;
typedef __attribute__((ext_vector_type(8))) short  short8;
typedef __attribute__((ext_vector_type(4))) short  short4v;

__device__ __forceinline__ float bf2f(short s){
  unsigned u = ((unsigned)(unsigned short)s) << 16;
  float f; __builtin_memcpy(&f, &u, 4); return f;
}
__device__ __forceinline__ short f2bf(float x){
  unsigned u; __builtin_memcpy(&u, &x, 4);
  u = (u + 0x7fffu + ((u >> 16) & 1u)) >> 16;
  return (short)u;
}
__device__ __forceinline__ float sigm(float x){ return 1.f / (1.f + __expf(-x)); }
__device__ __forceinline__ float ftanh(float x){ return 1.f - 2.f / (__expf(2.f * x) + 1.f); }

// L2-bypassing (agent-coherent) pipelined vector ops.
__device__ __forceinline__ short8 ld_b128_sc1(const short* p){
  short8 r;
  asm volatile("global_load_dwordx4 %0, %1, off sc1" : "=&v"(r) : "v"(p) : "memory");
  return r;
}
__device__ __forceinline__ void st_b64_sc1(short* p, unsigned long long v){
  asm volatile("global_store_dwordx2 %0, %1, off sc1" :: "v"(p), "v"(v) : "memory");
}
__device__ __forceinline__ void wait_vm0(){
  asm volatile("s_waitcnt vmcnt(0)" ::: "memory");
  __builtin_amdgcn_sched_barrier(0);
}
__device__ __forceinline__ void flag_pub(int* f, int v){
  __hip_atomic_store(f, v, __ATOMIC_RELAXED, __HIP_MEMORY_SCOPE_AGENT);
}
__device__ __forceinline__ int flag_ld(int* f){
  return __hip_atomic_load(f, __ATOMIC_RELAXED, __HIP_MEMORY_SCOPE_AGENT);
}

// ---------------------------------------------------------------------------
// Generic bf16-MFMA GEMM: C[M,N] = A[M,K] * B[K,N] + bias[N]
// ---------------------------------------------------------------------------
template<int AF32, int OF32>
__global__ __launch_bounds__(256) void gemm_bias(const void* __restrict__ Av,
                                                 const float* __restrict__ B,
                                                 const float* __restrict__ bias,
                                                 void* __restrict__ Cv,
                                                 int M, int N, int K)
{
  __shared__ __align__(16) short As[128 * 40];
  __shared__ __align__(16) short Bs[128 * 40];
  int tid  = threadIdx.x;
  int col0 = blockIdx.x * 128, row0 = blockIdx.y * 128;
  int lane = tid & 63, wave = tid >> 6;
  int wm = (wave >> 1) * 64, wn = (wave & 1) * 64;

  f32x4 acc[4][4];
  for (int mi = 0; mi < 4; mi++)
    for (int ni = 0; ni < 4; ni++)
      for (int q = 0; q < 4; q++) acc[mi][ni][q] = 0.f;

  for (int kt = 0; kt < K; kt += 32) {
    __syncthreads();
    if (AF32) {
      const float* A = (const float*)Av;
      for (int i = 0; i < 4; i++) {
        int idx = tid + i * 256;
        int r = idx >> 3, c4 = (idx & 7) << 2;
        f32x4 v = *(const f32x4*)(A + (size_t)(row0 + r) * K + kt + c4);
        short4v o;
        for (int q = 0; q < 4; q++) o[q] = f2bf(v[q]);
        *(short4v*)&As[r * 40 + c4] = o;
      }
    } else {
      const short* A = (const short*)Av;
      for (int i = 0; i < 2; i++) {
        int idx = tid + i * 256;
        int r = idx >> 2, c8 = (idx & 3) << 3;
        short8 v = *(const short8*)(A + (size_t)(row0 + r) * K + kt + c8);
        *(short8*)&As[r * 40 + c8] = v;
      }
    }
    for (int i = 0; i < 4; i++) {
      int idx = tid + i * 256;
      int kr = idx >> 5, c4 = (idx & 31) << 2;
      f32x4 v = *(const f32x4*)(B + (size_t)(kt + kr) * N + col0 + c4);
      for (int e = 0; e < 4; e++) Bs[(c4 + e) * 40 + kr] = f2bf(v[e]);
    }
    __syncthreads();

    int fr = lane & 15, fo = (lane >> 4) << 3;
    short8 af[4], bfr[4];
    for (int mi = 0; mi < 4; mi++) af[mi]  = *(short8*)&As[(wm + mi * 16 + fr) * 40 + fo];
    for (int ni = 0; ni < 4; ni++) bfr[ni] = *(short8*)&Bs[(wn + ni * 16 + fr) * 40 + fo];
    for (int mi = 0; mi < 4; mi++)
      for (int ni = 0; ni < 4; ni++)
        acc[mi][ni] = __builtin_amdgcn_mfma_f32_16x16x32_bf16(af[mi], bfr[ni], acc[mi][ni], 0, 0, 0);
  }

  int efr = lane & 15, efrow = (lane >> 4) << 2;
  for (int ni = 0; ni < 4; ni++) {
    int col = col0 + wn + ni * 16 + efr;
    float bv = bias[col];
    for (int mi = 0; mi < 4; mi++) {
      for (int q = 0; q < 4; q++) {
        int row = row0 + wm + mi * 16 + efrow + q;
        float v = acc[mi][ni][q] + bv;
        if (OF32) ((float*)Cv)[(size_t)row * N + col] = v;
        else      ((short*)Cv)[(size_t)row * N + col] = f2bf(v);
      }
    }
  }
}

// ---------------------------------------------------------------------------
// ws = s @ atW + atW_b
// ---------------------------------------------------------------------------
__global__ __launch_bounds__(128) void att_ws_kernel(const float* __restrict__ s,
                                                     const float* __restrict__ atW,
                                                     const float* __restrict__ atWb,
                                                     float* __restrict__ ws)
{
  int b = blockIdx.x, a = threadIdx.x;
  float acc = atWb[a];
  for (int k = 0; k < 128; k++) acc += s[b * 128 + k] * atW[k * 128 + a];
  ws[b * 128 + a] = acc;
}

// ---------------------------------------------------------------------------
// m0 scan (H=256): 4 blocks/dir x 512 thr. Swapped-operand MFMA:
// gates^T = Wh^T (regs, A) x h^T (LDS, B). D-frag: col=batch, rows=4 j's ->
// all 4 gates of a (batch,j) live in ONE thread's acc -> register-local
// epilogue, NO LDS gate transpose. Exchange: own 64-j quarter via sc1 stores
// + single-writer per-block step flags; partners staged via 3 pipelined sc1
// b128 loads into swizzled LDS.
// ---------------------------------------------------------------------------
__device__ __forceinline__ void scan_m0(const short* __restrict__ xg,
                                        const float* __restrict__ Wh,
                                        short* __restrict__ hall,
                                        int* __restrict__ flags,   // 4 slots, 16-int spacing
                                        int bk, int dir, char* hsb)
{
  constexpr int H = 256, C = 512, H4 = 1024, KB = 8;
  const int tid = threadIdx.x, lane = tid & 63, w = tid >> 6;
  const int l15 = lane & 15, rg = lane >> 4;
  const int jt = w & 3, bh = w >> 2;
  const int j0g = bk * 64, dircol = dir ? H : 0;
  const int jD = j0g + jt * 16 + rg * 4;      // thread's output j base (global)

  // A-frags (weights^T), loaded once: bw[g][kb][e] = Wh[kb*32+rg*8+e][g*H + j0g + jt*16 + l15]
  short8 bw[4][KB];
#pragma unroll
  for (int g = 0; g < 4; g++) {
    int colg = g * H + j0g + jt * 16 + l15;
#pragma unroll
    for (int kb = 0; kb < KB; kb++)
#pragma unroll
      for (int e = 0; e < 8; e++)
        bw[g][kb][e] = f2bf(Wh[(size_t)(kb * 32 + rg * 8 + e) * H4 + colg]);
  }

  float cst[2][4];
#pragma unroll
  for (int nt = 0; nt < 2; nt++)
#pragma unroll
    for (int q = 0; q < 4; q++) cst[nt][q] = 0.f;

  const int eb = tid & 63, jq = tid >> 6;     // staging mapping
  int p1 = (bk + 1) & 3, p2 = (bk + 2) & 3, p3 = (bk + 3) & 3;

  for (int s = 0; s < 512; s++) {
    int t = dir ? 511 - s : s;

    // xg prefetch: a,i,f,o for this thread's 8 cells (2 batches x 4 j)
    short4v xgp[4][2];
#pragma unroll
    for (int g = 0; g < 4; g++)
#pragma unroll
      for (int nt = 0; nt < 2; nt++)
        xgp[g][nt] = *(const short4v*)(xg + (size_t)(t * 64 + bh * 32 + nt * 16 + l15) * H4 + g * H + jD);

    f32x4 acc[4][2];
#pragma unroll
    for (int g = 0; g < 4; g++)
#pragma unroll
      for (int nt = 0; nt < 2; nt++)
#pragma unroll
        for (int q = 0; q < 4; q++) acc[g][nt][q] = 0.f;

    if (s > 0) {
#pragma unroll
      for (int kb = 0; kb < KB; kb++) {
        short8 bf[2];
#pragma unroll
        for (int nt = 0; nt < 2; nt++) {
          int row = bh * 32 + nt * 16 + l15;
          int ck = kb * 4 + rg;
          bf[nt] = *(const short8*)(hsb + row * 512 + (((ck ^ (row & 7))) << 4));
        }
#pragma unroll
        for (int g = 0; g < 4; g++) {
          acc[g][0] = __builtin_amdgcn_mfma_f32_16x16x32_bf16(bw[g][kb], bf[0], acc[g][0], 0, 0, 0);
          acc[g][1] = __builtin_amdgcn_mfma_f32_16x16x32_bf16(bw[g][kb], bf[1], acc[g][1], 0, 0, 0);
        }
      }
    }
    __syncthreads();   // all hsb reads of h_{t-1} done

    // register-local epilogue: 2 batches x 4 j per thread
#pragma unroll
    for (int nt = 0; nt < 2; nt++) {
      int batch = bh * 32 + nt * 16 + l15;
      unsigned long long hv = 0;
#pragma unroll
      for (int q = 0; q < 4; q++) {
        float a_ = acc[0][nt][q] + bf2f(xgp[0][nt][q]);
        float i_ = acc[1][nt][q] + bf2f(xgp[1][nt][q]);
        float f_ = acc[2][nt][q] + bf2f(xgp[2][nt][q]);
        float o_ = acc[3][nt][q] + bf2f(xgp[3][nt][q]);
        float cc = ftanh(a_) * sigm(i_) + cst[nt][q] * sigm(f_);
        cst[nt][q] = cc;
        hv |= ((unsigned long long)(unsigned short)f2bf(ftanh(cc) * sigm(o_))) << (16 * q);
      }
      // own quarter into LDS (swizzled) for next step
      int ck = jD >> 3;
      *(unsigned long long*)(hsb + batch * 512 + ((ck ^ (batch & 7)) << 4) + (rg & 1) * 8) = hv;
      // own quarter to global (partner exchange + attention), L2-bypassing
      st_b64_sc1(hall + (size_t)(t * 64 + batch) * C + dircol + jD, hv);
    }

    if (s < 511) {
      wait_vm0();          // per-wave drain of own sc1 stores
      __syncthreads();     // ALL waves drained before publish
      if (tid == 0) flag_pub(flags + bk * 16, s + 1);
      while (flag_ld(flags + p1 * 16) <= s ||
             flag_ld(flags + p2 * 16) <= s ||
             flag_ld(flags + p3 * 16) <= s)
        __builtin_amdgcn_s_sleep(2);
      // stage 3 partner quarters: thread -> (row eb, 16B chunk jq) per quarter
      const short* hrow = hall + (size_t)(t * 64 + eb) * C + dircol;
      short8 v1 = ld_b128_sc1(hrow + p1 * 64 + jq * 8);
      short8 v2 = ld_b128_sc1(hrow + p2 * 64 + jq * 8);
      short8 v3 = ld_b128_sc1(hrow + p3 * 64 + jq * 8);
      wait_vm0();
      *(short8*)(hsb + eb * 512 + (((p1 * 8 + jq) ^ (eb & 7)) << 4)) = v1;
      *(short8*)(hsb + eb * 512 + (((p2 * 8 + jq) ^ (eb & 7)) << 4)) = v2;
      *(short8*)(hsb + eb * 512 + (((p3 * 8 + jq) ^ (eb & 7)) << 4)) = v3;
      __syncthreads();     // hsb fully populated for step s+1
    }
  }
}

// ---------------------------------------------------------------------------
// m1 scan (H=128): ONE block per direction, all-LDS h, swapped-operand MFMA,
// register-local epilogue, zero cross-block traffic.
// ---------------------------------------------------------------------------
__device__ __forceinline__ void scan_m1(const short* __restrict__ xg,
                                        const float* __restrict__ Wh,
                                        short* __restrict__ hall,
                                        int dir, char* hsb)
{
  constexpr int H = 128, C = 256, H4 = 512, KB = 4;
  const int tid = threadIdx.x, lane = tid & 63, w = tid >> 6;
  const int l15 = lane & 15, rg = lane >> 4;
  const int dircol = dir ? H : 0;
  const int jD = w * 16 + rg * 4;             // thread's output j base

  short8 bw[4][KB];
#pragma unroll
  for (int g = 0; g < 4; g++) {
    int colg = g * H + w * 16 + l15;
#pragma unroll
    for (int kb = 0; kb < KB; kb++)
#pragma unroll
      for (int e = 0; e < 8; e++)
        bw[g][kb][e] = f2bf(Wh[(size_t)(kb * 32 + rg * 8 + e) * H4 + colg]);
  }

  float cst[4][4];
#pragma unroll
  for (int nt = 0; nt < 4; nt++)
#pragma unroll
    for (int q = 0; q < 4; q++) cst[nt][q] = 0.f;

  for (int s = 0; s < 512; s++) {
    int t = dir ? 511 - s : s;
    short4v xgp[4][4];
#pragma unroll
    for (int g = 0; g < 4; g++)
#pragma unroll
      for (int nt = 0; nt < 4; nt++)
        xgp[g][nt] = *(const short4v*)(xg + (size_t)(t * 64 + nt * 16 + l15) * H4 + g * H + jD);

    f32x4 acc[4][4];
#pragma unroll
    for (int g = 0; g < 4; g++)
#pragma unroll
      for (int nt = 0; nt < 4; nt++)
#pragma unroll
        for (int q = 0; q < 4; q++) acc[g][nt][q] = 0.f;

    if (s > 0) {
#pragma unroll
      for (int kb = 0; kb < KB; kb++) {
        short8 bf[4];
#pragma unroll
        for (int nt = 0; nt < 4; nt++) {
          int row = nt * 16 + l15;
          int ck = kb * 4 + rg;
          bf[nt] = *(const short8*)(hsb + row * 256 + ((ck ^ (row & 7)) << 4));
        }
#pragma unroll
        for (int g = 0; g < 4; g++)
#pragma unroll
          for (int nt = 0; nt < 4; nt++)
            acc[g][nt] = __builtin_amdgcn_mfma_f32_16x16x32_bf16(bw[g][kb], bf[nt], acc[g][nt], 0, 0, 0);
      }
    }
    __syncthreads();

#pragma unroll
    for (int nt = 0; nt < 4; nt++) {
      int batch = nt * 16 + l15;
      unsigned long long hv = 0;
#pragma unroll
      for (int q = 0; q < 4; q++) {
        float a_ = acc[0][nt][q] + bf2f(xgp[0][nt][q]);
        float i_ = acc[1][nt][q] + bf2f(xgp[1][nt][q]);
        float f_ = acc[2][nt][q] + bf2f(xgp[2][nt][q]);
        float o_ = acc[3][nt][q] + bf2f(xgp[3][nt][q]);
        float cc = ftanh(a_) * sigm(i_) + cst[nt][q] * sigm(f_);
        cst[nt][q] = cc;
        hv |= ((unsigned long long)(unsigned short)f2bf(ftanh(cc) * sigm(o_))) << (16 * q);
      }
      int ck = jD >> 3;
      *(unsigned long long*)(hsb + batch * 256 + ((ck ^ (batch & 7)) << 4) + (rg & 1) * 8) = hv;
      *(unsigned long long*)(hall + (size_t)(t * 64 + batch) * C + dircol + jD) = hv;  // plain (post-kernel readers)
    }
    __syncthreads();
  }
}

__global__ __launch_bounds__(512, 1) void lstm_persistent(
    const short* __restrict__ xgf0, const short* __restrict__ xgb0,
    const short* __restrict__ xgf1, const short* __restrict__ xgb1,
    const float* __restrict__ fh0, const float* __restrict__ bh0,
    const float* __restrict__ fh1, const float* __restrict__ bh1,
    short* __restrict__ hall0, short* __restrict__ hall1, int* __restrict__ bar)
{
  __shared__ __align__(16) char hsb[64 * 512];
  int bx = blockIdx.x;
  if (bx < 8) {
    int dir = bx >> 2, bk = bx & 3;
    scan_m0(dir ? xgb0 : xgf0, dir ? bh0 : fh0, hall0,
            bar + dir * 64, bk, dir, hsb);
  } else {
    int dir = bx - 8;
    scan_m1(dir ? xgb1 : xgf1, dir ? bh1 : fh1, hall1, dir, hsb);
  }
}

// ---------------------------------------------------------------------------
// logits[r] = tanh(vh[r,:] + ws[b,:]) . atw + atw_b
// ---------------------------------------------------------------------------
__global__ __launch_bounds__(256) void logits_kernel(const float* __restrict__ vh,
                                                     const float* __restrict__ ws,
                                                     const float* __restrict__ atw,
                                                     const float* __restrict__ atwb,
                                                     float* __restrict__ lg)
{
  int wid  = (int)((blockIdx.x * 256 + threadIdx.x) >> 6);
  int lane = threadIdx.x & 63;
  if (wid >= 32768) return;
  int b = wid & 63;
  float x0 = vh[(size_t)wid * 128 + lane]      + ws[b * 128 + lane];
  float x1 = vh[(size_t)wid * 128 + 64 + lane] + ws[b * 128 + 64 + lane];
  float v = ftanh(x0) * atw[lane] + ftanh(x1) * atw[64 + lane];
  for (int off = 32; off; off >>= 1) v += __shfl_down(v, off);
  if (lane == 0) lg[wid] = v + atwb[0];
}

// ---------------------------------------------------------------------------
// Per-batch softmax over T + context
// ---------------------------------------------------------------------------
__global__ __launch_bounds__(256) void softmax_ctx(const float* __restrict__ lg,
                                                   const short* __restrict__ hall,
                                                   float* __restrict__ ctx, int C)
{
  int b = blockIdx.x, tid = threadIdx.x, lane = tid & 63, wv = tid >> 6;
  __shared__ float ebuf[512];
  __shared__ float red[8];
  float l0 = lg[tid * 64 + b];
  float l1 = lg[(tid + 256) * 64 + b];
  float m = fmaxf(l0, l1);
  for (int o = 32; o; o >>= 1) m = fmaxf(m, __shfl_xor(m, o));
  if (lane == 0) red[wv] = m;
  __syncthreads();
  m = fmaxf(fmaxf(red[0], red[1]), fmaxf(red[2], red[3]));
  float e0 = __expf(l0 - m), e1 = __expf(l1 - m);
  ebuf[tid] = e0; ebuf[tid + 256] = e1;
  float sm = e0 + e1;
  for (int o = 32; o; o >>= 1) sm += __shfl_xor(sm, o);
  if (lane == 0) red[4 + wv] = sm;
  __syncthreads();
  sm = red[4] + red[5] + red[6] + red[7];
  float inv = 1.f / (sm * 512.f);
  for (int c = tid; c < C; c += 256) {
    float acc = 0.f;
    const short* hp = hall + (size_t)b * C + c;
    for (int t = 0; t < 512; t++) acc += ebuf[t] * bf2f(hp[(size_t)t * 64 * C]);
    ctx[b * C + c] = acc * inv;
  }
}

// ---------------------------------------------------------------------------
__global__ __launch_bounds__(256) void final_kernel(const float* __restrict__ ctx0,
                                                    const float* __restrict__ ctx1,
                                                    const float* __restrict__ w0,
                                                    const float* __restrict__ b0,
                                                    const float* __restrict__ w1,
                                                    const float* __restrict__ b1,
                                                    float* __restrict__ out)
{
  int b = blockIdx.x, o = threadIdx.x;
  float acc = b0[o] + b1[o];
  for (int c = 0; c < 512; c++) acc += ctx0[b * 512 + c] * w0[c * 256 + o];
  for (int c = 0; c < 256; c++) acc += ctx1[b * 256 + c] * w1[c * 256 + o];
  out[b * 256 + o] = ftanh(acc);
}

// ---------------------------------------------------------------------------
extern "C" void kernel_launch(void* const* d_in, const int* in_sizes, int n_in,
                              void* d_out, int out_size, void* d_ws, size_t ws_size,
                              hipStream_t stream)
{
  const float* x0    = (const float*)d_in[0];
  const float* x1    = (const float*)d_in[1];
  const float* sIn   = (const float*)d_in[2];
  const float* emb_w0 = (const float*)d_in[3];  const float* emb_b0 = (const float*)d_in[4];
  const float* fx_w0  = (const float*)d_in[5];  const float* fx_b0  = (const float*)d_in[6];
  const float* fh_w0  = (const float*)d_in[7];
  const float* bx_w0  = (const float*)d_in[8];  const float* bx_b0  = (const float*)d_in[9];
  const float* bh_w0  = (const float*)d_in[10];
  const float* atV_w0 = (const float*)d_in[11]; const float* atV_b0 = (const float*)d_in[12];
  const float* atW_w0 = (const float*)d_in[13]; const float* atW_b0 = (const float*)d_in[14];
  const float* atw_w0 = (const float*)d_in[15]; const float* atw_b0 = (const float*)d_in[16];
  const float* lgd_w0 = (const float*)d_in[17]; const float* lgd_b0 = (const float*)d_in[18];
  const float* emb_w1 = (const float*)d_in[19]; const float* emb_b1 = (const float*)d_in[20];
  const float* fx_w1  = (const float*)d_in[21]; const float* fx_b1  = (const float*)d_in[22];
  const float* fh_w1  = (const float*)d_in[23];
  const float* bx_w1  = (const float*)d_in[24]; const float* bx_b1  = (const float*)d_in[25];
  const float* bh_w1  = (const float*)d_in[26];
  const float* atV_w1 = (const float*)d_in[27]; const float* atV_b1 = (const float*)d_in[28];
  const float* atW_w1 = (const float*)d_in[29]; const float* atW_b1 = (const float*)d_in[30];
  const float* atw_w1 = (const float*)d_in[31]; const float* atw_b1 = (const float*)d_in[32];
  const float* lgd_w1 = (const float*)d_in[33]; const float* lgd_b1 = (const float*)d_in[34];
  float* out = (float*)d_out;

  char* wp = (char*)d_ws;
  auto alloc = [&](size_t bytes) -> void* {
    void* p = wp; wp += (bytes + 255) & ~(size_t)255; return p;
  };
  int*   bar   = (int*)alloc(1024);
  short* h0_0  = (short*)alloc(32768ull * 512 * 2);
  short* h0_1  = (short*)alloc(32768ull * 128 * 2);
  short* xgf0  = (short*)alloc(32768ull * 1024 * 2);
  short* xgb0  = (short*)alloc(32768ull * 1024 * 2);
  short* xgf1  = (short*)alloc(32768ull * 512 * 2);
  short* xgb1  = (short*)alloc(32768ull * 512 * 2);
  short* hall0 = (short*)alloc(32768ull * 512 * 2);
  short* hall1 = (short*)alloc(32768ull * 256 * 2);
  float* vh0   = (float*)alloc(32768ull * 128 * 4);
  float* vh1   = (float*)alloc(32768ull * 128 * 4);
  float* wsb0  = (float*)alloc(64 * 128 * 4);
  float* wsb1  = (float*)alloc(64 * 128 * 4);
  float* lg0   = (float*)alloc(32768 * 4);
  float* lg1   = (float*)alloc(32768 * 4);
  float* ctx0  = (float*)alloc(64 * 512 * 4);
  float* ctx1  = (float*)alloc(64 * 256 * 4);

  // embeddings (f32 in, bf16 out)
  gemm_bias<1, 0><<<dim3(4, 256), 256, 0, stream>>>(x0, emb_w0, emb_b0, h0_0, 32768, 512, 2048);
  gemm_bias<1, 0><<<dim3(1, 256), 256, 0, stream>>>(x1, emb_w1, emb_b1, h0_1, 32768, 128, 128);
  // input projections (bf16 in, bf16 out)
  gemm_bias<0, 0><<<dim3(8, 256), 256, 0, stream>>>(h0_0, fx_w0, fx_b0, xgf0, 32768, 1024, 512);
  gemm_bias<0, 0><<<dim3(8, 256), 256, 0, stream>>>(h0_0, bx_w0, bx_b0, xgb0, 32768, 1024, 512);
  gemm_bias<0, 0><<<dim3(4, 256), 256, 0, stream>>>(h0_1, fx_w1, fx_b1, xgf1, 32768, 512, 128);
  gemm_bias<0, 0><<<dim3(4, 256), 256, 0, stream>>>(h0_1, bx_w1, bx_b1, xgb1, 32768, 512, 128);
  // attention s-projection
  att_ws_kernel<<<64, 128, 0, stream>>>(sIn, atW_w0, atW_b0, wsb0);
  att_ws_kernel<<<64, 128, 0, stream>>>(sIn, atW_w1, atW_b1, wsb1);

  // persistent bidirectional LSTM scans
  hipMemsetAsync(bar, 0, 1024, stream);
  lstm_persistent<<<10, 512, 0, stream>>>(xgf0, xgb0, xgf1, xgb1,
                                          fh_w0, bh_w0, fh_w1, bh_w1,
                                          hall0, hall1, bar);

  // attention
  gemm_bias<0, 1><<<dim3(1, 256), 256, 0, stream>>>(hall0, atV_w0, atV_b0, vh0, 32768, 128, 512);
  gemm_bias<0, 1><<<dim3(1, 256), 256, 0, stream>>>(hall1, atV_w1, atV_b1, vh1, 32768, 128, 256);
  logits_kernel<<<8192, 256, 0, stream>>>(vh0, wsb0, atw_w0, atw_b0, lg0);
  logits_kernel<<<8192, 256, 0, stream>>>(vh1, wsb1, atw_w1, atw_b1, lg1);
  softmax_ctx<<<64, 256, 0, stream>>>(lg0, hall0, ctx0, 512);
  softmax_ctx<<<64, 256, 0, stream>>>(lg1, hall1, ctx1, 256);
  final_kernel<<<64, 256, 0, stream>>>(ctx0, ctx1, lgd_w0, lgd_b0, lgd_w1, lgd_b1, out);
}